// Round 12
// baseline (1771.292 us; speedup 1.0000x reference)
//
#include <hip/hip_runtime.h>
#include <cstdio>

#define NN 50000
#define EE 800000
#define GG 256
#define IND 32
#define HID 108
#define NL 4

__global__ void k_zero(int* deg) {
    int i = blockIdx.x * 256 + threadIdx.x;
    if (i < NN) deg[i] = 0;
}

__global__ void k_hist(const int* dst, int* deg) {
    int e = blockIdx.x * 256 + threadIdx.x;
    if (e < EE) atomicAdd(&deg[dst[e]], 1);
}

__global__ void k_scan(const int* deg, int* rp) {
    __shared__ int s[1024];
    __shared__ int carry;
    int tid = threadIdx.x;
    if (tid == 0) { carry = 0; rp[0] = 0; }
    __syncthreads();
    for (int base = 0; base < NN; base += 1024) {
        int i = base + tid;
        s[tid] = (i < NN) ? deg[i] : 0;
        __syncthreads();
        for (int off = 1; off < 1024; off <<= 1) {
            int t = (tid >= off) ? s[tid - off] : 0;
            __syncthreads();
            s[tid] += t;
            __syncthreads();
        }
        int cb = carry;
        __syncthreads();
        if (i < NN) rp[i + 1] = cb + s[tid];
        if (tid == 0) carry = cb + s[1023];
        __syncthreads();
    }
}

__global__ void k_scatter(const int* src, const int* dst, const int* rp,
                          int* deg, int* cs) {
    int e = blockIdx.x * 256 + threadIdx.x;
    if (e < EE) {
        int d = dst[e];
        int pos = atomicSub(&deg[d], 1) - 1;
        cs[rp[d] + pos] = src[e];
    }
}

// h[n][c] = feat[n][:] @ W_emb[:][c] + b[c]   (all fp32)
__global__ void k_embed(const float* feat, const float* W,
                        const float* b, float* h) {
    int i = blockIdx.x * 256 + threadIdx.x;
    if (i >= NN * HID) return;
    int n = i / HID, c = i - n * HID;
    float acc = b[c];
    const float* fr = feat + (size_t)n * IND;
    for (int k = 0; k < IND; k++) acc += fr[k] * W[k * HID + c];
    h[i] = acc;
}

// hp[n][c] = relu(h[n][:] @ Wp[:][c] + b[c])
__global__ void k_pool(const float* h, const float* W,
                       const float* b, float* hp) {
    int i = blockIdx.x * 256 + threadIdx.x;
    if (i >= NN * HID) return;
    int n = i / HID, c = i - n * HID;
    float acc = b[c];
    const float* hr = h + (size_t)n * HID;
    for (int k = 0; k < HID; k++) acc += hr[k] * W[k * HID + c];
    hp[i] = fmaxf(acc, 0.f);
}

// One block (128 thr) per node: agg = mean over in-neighbors of hp;
// bundle = [h | agg] @ W + b; h[n] += relu(l2norm(bundle)). In-place safe.
__global__ void k_app(const float* h, const float* hp,
                      const int* rp, const int* cs,
                      const float* W, const float* b,
                      float* hout) {
    __shared__ float hs[HID];
    __shared__ float as[HID];
    __shared__ float red[128];
    int n = blockIdx.x, c = threadIdx.x;
    if (c < HID) {
        hs[c] = h[(size_t)n * HID + c];
        float s = 0.f;
        int s0 = rp[n], s1 = rp[n + 1];
        for (int e = s0; e < s1; e++) s += hp[(size_t)cs[e] * HID + c];
        int dg = s1 - s0;
        as[c] = s / (float)((dg > 1) ? dg : 1);
    }
    __syncthreads();
    float bu = 0.f;
    if (c < HID) {
        bu = b[c];
        for (int k = 0; k < HID; k++) bu += hs[k] * W[k * HID + c];
        for (int k = 0; k < HID; k++) bu += as[k] * W[(HID + k) * HID + c];
    }
    red[c] = (c < HID) ? bu * bu : 0.f;
    __syncthreads();
    for (int off = 64; off > 0; off >>= 1) {
        if (c < off) red[c] += red[c + off];
        __syncthreads();
    }
    if (c < HID) {
        float inv = 1.0f / fmaxf(sqrtf(red[0]), 1e-12f);
        float v = fmaxf(bu * inv, 0.f);
        hout[(size_t)n * HID + c] = hs[c] + v;
    }
}

// Output is FLOAT32 (reference returns fp32 logits; harness reads fp32).
__global__ void k_readout(const float* h, const int* gid,
                          const float* W1, const float* b1,
                          const float* W2, const float* b2,
                          const float* W3, const float* b3,
                          float* out) {
    __shared__ float hg[HID];
    __shared__ float y1[54];
    __shared__ float y2[27];
    __shared__ int se[2];
    int g = blockIdx.x, tid = threadIdx.x;
    if (tid < 2) {
        int key = g + tid, lo = 0, hi = NN;
        while (lo < hi) {
            int mid = (lo + hi) >> 1;
            if (gid[mid] < key) lo = mid + 1; else hi = mid;
        }
        se[tid] = lo;
    }
    __syncthreads();
    int s = se[0], e = se[1];
    if (tid < HID) {
        float acc = 0.f;
        for (int n = s; n < e; n++) acc += h[(size_t)n * HID + tid];
        int cnt = e - s;
        hg[tid] = acc / (float)((cnt > 1) ? cnt : 1);
    }
    __syncthreads();
    if (tid < 54) {
        float a = b1[tid];
        for (int k = 0; k < HID; k++) a += hg[k] * W1[k * 54 + tid];
        y1[tid] = fmaxf(a, 0.f);
    }
    __syncthreads();
    if (tid < 27) {
        float a = b2[tid];
        for (int k = 0; k < 54; k++) a += y1[k] * W2[k * 27 + tid];
        y2[tid] = fmaxf(a, 0.f);
    }
    __syncthreads();
    if (tid < 10) {
        float a = b3[tid];
        for (int k = 0; k < 27; k++) a += y2[k] * W3[k * 10 + tid];
        out[g * 10 + tid] = a;
    }
}

extern "C" void kernel_launch(void* const* d_in, const int* in_sizes, int n_in,
                              void* d_out, int out_size, void* d_ws, size_t ws_size,
                              hipStream_t stream) {
    float* out = (float*)d_out;
    (void)in_sizes; (void)n_in; (void)ws_size; (void)out_size;

    hipStreamCaptureStatus cap = hipStreamCaptureStatusNone;
    (void)hipStreamIsCapturing(stream, &cap);
    int diag = (cap == hipStreamCaptureStatusNone);

    const float* feat   = (const float*)d_in[0];
    const int*   src    = (const int*)d_in[4];
    const int*   dst    = (const int*)d_in[5];
    const int*   gid    = (const int*)d_in[6];
    const float* W_emb  = (const float*)d_in[7];
    const float* b_emb  = (const float*)d_in[8];
    const float* W_pool = (const float*)d_in[9];
    const float* b_pool = (const float*)d_in[10];
    const float* W_app  = (const float*)d_in[11];
    const float* b_app  = (const float*)d_in[12];
    const float* W1     = (const float*)d_in[13];
    const float* b1     = (const float*)d_in[14];
    const float* W2     = (const float*)d_in[15];
    const float* b2     = (const float*)d_in[16];
    const float* W3     = (const float*)d_in[17];
    const float* b3     = (const float*)d_in[18];

    char* ws = (char*)d_ws;
    size_t off = 0;
    float* h  = (float*)(ws + off); off += ((size_t)NN * HID * 4 + 255) & ~(size_t)255;
    float* hp = (float*)(ws + off); off += ((size_t)NN * HID * 4 + 255) & ~(size_t)255;
    int* cs   = (int*)(ws + off);   off += ((size_t)EE * 4 + 255) & ~(size_t)255;
    int* deg  = (int*)(ws + off);   off += ((size_t)NN * 4 + 255) & ~(size_t)255;
    int* rp   = (int*)(ws + off);   off += ((size_t)(NN + 1) * 4 + 255) & ~(size_t)255;

    int eblk = (NN * HID + 255) / 256;

    hipLaunchKernelGGL(k_zero, dim3((NN + 255) / 256), dim3(256), 0, stream, deg);
    hipLaunchKernelGGL(k_hist, dim3((EE + 255) / 256), dim3(256), 0, stream, dst, deg);
    hipLaunchKernelGGL(k_scan, dim3(1), dim3(1024), 0, stream, deg, rp);
    hipLaunchKernelGGL(k_scatter, dim3((EE + 255) / 256), dim3(256), 0, stream,
                       src, dst, rp, deg, cs);

    hipLaunchKernelGGL(k_embed, dim3(eblk), dim3(256), 0, stream, feat, W_emb, b_emb, h);
    for (int l = 0; l < NL; l++) {
        hipLaunchKernelGGL(k_pool, dim3(eblk), dim3(256), 0, stream,
                           h, W_pool + (size_t)l * HID * HID, b_pool + (size_t)l * HID, hp);
        hipLaunchKernelGGL(k_app, dim3(NN), dim3(128), 0, stream,
                           h, hp, rp, cs,
                           W_app + (size_t)l * 2 * HID * HID, b_app + (size_t)l * HID, h);
    }
    hipLaunchKernelGGL(k_readout, dim3(GG), dim3(128), 0, stream,
                       h, gid, W1, b1, W2, b2, W3, b3, out);

    if (diag) {
        static float o4[4];
        (void)hipStreamSynchronize(stream);
        (void)hipMemcpyAsync(o4, out, 16, hipMemcpyDeviceToHost, stream);
        (void)hipStreamSynchronize(stream);
        fprintf(stderr, "[GS] out_f32=[%.6f %.6f %.6f %.6f]\n", o4[0], o4[1], o4[2], o4[3]);
        fflush(stderr);
    }
}

// Round 13
// 1561.740 us; speedup vs baseline: 1.1342x; 1.1342x over previous
//
#include <hip/hip_runtime.h>
#include <cstdio>

#define NN 50000
#define EE 800000
#define GG 256
#define IND 32
#define HID 108
#define NL 4

__global__ void k_zero(int* deg) {
    int i = blockIdx.x * 256 + threadIdx.x;
    if (i < NN) deg[i] = 0;
}

__global__ void k_hist(const int* dst, int* deg) {
    int e = blockIdx.x * 256 + threadIdx.x;
    if (e < EE) atomicAdd(&deg[dst[e]], 1);
}

__global__ void k_scan(const int* deg, int* rp) {
    __shared__ int s[1024];
    __shared__ int carry;
    int tid = threadIdx.x;
    if (tid == 0) { carry = 0; rp[0] = 0; }
    __syncthreads();
    for (int base = 0; base < NN; base += 1024) {
        int i = base + tid;
        s[tid] = (i < NN) ? deg[i] : 0;
        __syncthreads();
        for (int off = 1; off < 1024; off <<= 1) {
            int t = (tid >= off) ? s[tid - off] : 0;
            __syncthreads();
            s[tid] += t;
            __syncthreads();
        }
        int cb = carry;
        __syncthreads();
        if (i < NN) rp[i + 1] = cb + s[tid];
        if (tid == 0) carry = cb + s[1023];
        __syncthreads();
    }
}

__global__ void k_scatter(const int* src, const int* dst, const int* rp,
                          int* deg, int* cs) {
    int e = blockIdx.x * 256 + threadIdx.x;
    if (e < EE) {
        int d = dst[e];
        int pos = atomicSub(&deg[d], 1) - 1;
        cs[rp[d] + pos] = src[e];
    }
}

__global__ void k_embed(const float* feat, const float* W,
                        const float* b, float* h) {
    int i = blockIdx.x * 256 + threadIdx.x;
    if (i >= NN * HID) return;
    int n = i / HID, c = i - n * HID;
    float acc = b[c];
    const float* fr = feat + (size_t)n * IND;
    for (int k = 0; k < IND; k++) acc += fr[k] * W[k * HID + c];
    h[i] = acc;
}

// pool GEMM: W staged in LDS once per block; two nodes per iteration,
// grid-stride. hp[n][c] = relu(h[n][:] @ W[:][c] + b[c])
__global__ __launch_bounds__(256)
void k_pool(const float* __restrict__ h, const float* __restrict__ W,
            const float* __restrict__ b, float* __restrict__ hp, int nblocks) {
    __shared__ float Wl[HID * HID];
    __shared__ float hrow[2][HID];
    int tid = threadIdx.x;
    for (int i = tid; i < HID * HID; i += 256) Wl[i] = W[i];
    int r = tid / HID, c = tid - r * HID;    // r<2, c<108 for tid<216
    float bc = (tid < 216) ? b[c] : 0.f;
    for (int base = blockIdx.x * 2; base < NN; base += nblocks * 2) {
        __syncthreads();
        if (tid < 216) {
            int n = base + r;
            hrow[r][c] = (n < NN) ? h[(size_t)n * HID + c] : 0.f;
        }
        __syncthreads();
        if (tid < 216) {
            int n = base + r;
            if (n < NN) {
                float acc = bc;
                const float* hr = hrow[r];
                #pragma unroll 4
                for (int k = 0; k < HID; k++) acc += hr[k] * Wl[k * HID + c];
                hp[(size_t)n * HID + c] = fmaxf(acc, 0.f);
            }
        }
    }
}

// app: one block (128 thr) per node.
// Gather phase: 4 edge-slices (q) x 32 col-lanes (t), float4 loads (t<27).
// Then bundle GEMM (W from global, L2-resident), l2norm, relu, residual.
__global__ __launch_bounds__(128)
void k_app(const float* __restrict__ h, const float* __restrict__ hp,
           const int* __restrict__ rp, const int* __restrict__ cs,
           const float* __restrict__ W, const float* __restrict__ b,
           float* __restrict__ hout) {
    __shared__ float asl[4][HID];
    __shared__ float hs[HID];
    __shared__ float as[HID];
    __shared__ float red[128];
    int n = blockIdx.x, tid = threadIdx.x;
    int t = tid & 31, q = tid >> 5;
    int s0 = rp[n], s1 = rp[n + 1];

    float a0 = 0.f, a1 = 0.f, a2 = 0.f, a3 = 0.f;
    if (t < 27) {
        int coff = 4 * t;
        int e = s0 + q;
        // unroll x2: two independent gathers in flight per thread
        for (; e + 4 < s1; e += 8) {
            const float4 v0 = *(const float4*)(hp + (size_t)cs[e] * HID + coff);
            const float4 v1 = *(const float4*)(hp + (size_t)cs[e + 4] * HID + coff);
            a0 += v0.x + v1.x; a1 += v0.y + v1.y;
            a2 += v0.z + v1.z; a3 += v0.w + v1.w;
        }
        if (e < s1) {
            const float4 v0 = *(const float4*)(hp + (size_t)cs[e] * HID + coff);
            a0 += v0.x; a1 += v0.y; a2 += v0.z; a3 += v0.w;
        }
        asl[q][coff] = a0; asl[q][coff + 1] = a1;
        asl[q][coff + 2] = a2; asl[q][coff + 3] = a3;
    }
    if (tid < HID) hs[tid] = h[(size_t)n * HID + tid];
    __syncthreads();
    if (tid < HID) {
        int dg = s1 - s0;
        float inv = 1.0f / (float)((dg > 1) ? dg : 1);
        as[tid] = (asl[0][tid] + asl[1][tid] + asl[2][tid] + asl[3][tid]) * inv;
    }
    __syncthreads();

    float bu = 0.f;
    int c = tid;
    if (c < HID) {
        bu = b[c];
        #pragma unroll 4
        for (int k = 0; k < HID; k++) bu += hs[k] * W[k * HID + c];
        #pragma unroll 4
        for (int k = 0; k < HID; k++) bu += as[k] * W[(HID + k) * HID + c];
    }
    red[tid] = (c < HID) ? bu * bu : 0.f;
    __syncthreads();
    for (int off = 64; off > 0; off >>= 1) {
        if (tid < off) red[tid] += red[tid + off];
        __syncthreads();
    }
    if (c < HID) {
        float inv = 1.0f / fmaxf(sqrtf(red[0]), 1e-12f);
        float v = fmaxf(bu * inv, 0.f);
        hout[(size_t)n * HID + c] = hs[c] + v;
    }
}

__global__ void k_readout(const float* h, const int* gid,
                          const float* W1, const float* b1,
                          const float* W2, const float* b2,
                          const float* W3, const float* b3,
                          float* out) {
    __shared__ float hg[HID];
    __shared__ float y1[54];
    __shared__ float y2[27];
    __shared__ int se[2];
    int g = blockIdx.x, tid = threadIdx.x;
    if (tid < 2) {
        int key = g + tid, lo = 0, hi = NN;
        while (lo < hi) {
            int mid = (lo + hi) >> 1;
            if (gid[mid] < key) lo = mid + 1; else hi = mid;
        }
        se[tid] = lo;
    }
    __syncthreads();
    int s = se[0], e = se[1];
    if (tid < HID) {
        float acc = 0.f;
        for (int n = s; n < e; n++) acc += h[(size_t)n * HID + tid];
        int cnt = e - s;
        hg[tid] = acc / (float)((cnt > 1) ? cnt : 1);
    }
    __syncthreads();
    if (tid < 54) {
        float a = b1[tid];
        for (int k = 0; k < HID; k++) a += hg[k] * W1[k * 54 + tid];
        y1[tid] = fmaxf(a, 0.f);
    }
    __syncthreads();
    if (tid < 27) {
        float a = b2[tid];
        for (int k = 0; k < 54; k++) a += y1[k] * W2[k * 27 + tid];
        y2[tid] = fmaxf(a, 0.f);
    }
    __syncthreads();
    if (tid < 10) {
        float a = b3[tid];
        for (int k = 0; k < 27; k++) a += y2[k] * W3[k * 10 + tid];
        out[g * 10 + tid] = a;
    }
}

extern "C" void kernel_launch(void* const* d_in, const int* in_sizes, int n_in,
                              void* d_out, int out_size, void* d_ws, size_t ws_size,
                              hipStream_t stream) {
    float* out = (float*)d_out;
    (void)in_sizes; (void)n_in; (void)ws_size; (void)out_size;

    const float* feat   = (const float*)d_in[0];
    const int*   src    = (const int*)d_in[4];
    const int*   dst    = (const int*)d_in[5];
    const int*   gid    = (const int*)d_in[6];
    const float* W_emb  = (const float*)d_in[7];
    const float* b_emb  = (const float*)d_in[8];
    const float* W_pool = (const float*)d_in[9];
    const float* b_pool = (const float*)d_in[10];
    const float* W_app  = (const float*)d_in[11];
    const float* b_app  = (const float*)d_in[12];
    const float* W1     = (const float*)d_in[13];
    const float* b1     = (const float*)d_in[14];
    const float* W2     = (const float*)d_in[15];
    const float* b2     = (const float*)d_in[16];
    const float* W3     = (const float*)d_in[17];
    const float* b3     = (const float*)d_in[18];

    char* ws = (char*)d_ws;
    size_t off = 0;
    float* h  = (float*)(ws + off); off += ((size_t)NN * HID * 4 + 255) & ~(size_t)255;
    float* hp = (float*)(ws + off); off += ((size_t)NN * HID * 4 + 255) & ~(size_t)255;
    int* cs   = (int*)(ws + off);   off += ((size_t)EE * 4 + 255) & ~(size_t)255;
    int* deg  = (int*)(ws + off);   off += ((size_t)NN * 4 + 255) & ~(size_t)255;
    int* rp   = (int*)(ws + off);   off += ((size_t)(NN + 1) * 4 + 255) & ~(size_t)255;

    int eblk = (NN * HID + 255) / 256;
    const int POOL_BLOCKS = 768;   // 3 blocks/CU at 47.6 KB LDS

    hipLaunchKernelGGL(k_zero, dim3((NN + 255) / 256), dim3(256), 0, stream, deg);
    hipLaunchKernelGGL(k_hist, dim3((EE + 255) / 256), dim3(256), 0, stream, dst, deg);
    hipLaunchKernelGGL(k_scan, dim3(1), dim3(1024), 0, stream, deg, rp);
    hipLaunchKernelGGL(k_scatter, dim3((EE + 255) / 256), dim3(256), 0, stream,
                       src, dst, rp, deg, cs);

    hipLaunchKernelGGL(k_embed, dim3(eblk), dim3(256), 0, stream, feat, W_emb, b_emb, h);
    for (int l = 0; l < NL; l++) {
        hipLaunchKernelGGL(k_pool, dim3(POOL_BLOCKS), dim3(256), 0, stream,
                           h, W_pool + (size_t)l * HID * HID, b_pool + (size_t)l * HID,
                           hp, POOL_BLOCKS);
        hipLaunchKernelGGL(k_app, dim3(NN), dim3(128), 0, stream,
                           h, hp, rp, cs,
                           W_app + (size_t)l * 2 * HID * HID, b_app + (size_t)l * HID, h);
    }
    hipLaunchKernelGGL(k_readout, dim3(GG), dim3(128), 0, stream,
                       h, gid, W1, b1, W2, b2, W3, b3, out);
}